// Round 7
// baseline (879.914 us; speedup 1.0000x reference)
//
#include <hip/hip_runtime.h>
#include <hip/hip_bf16.h>
#include <math.h>

#define T_SEQ 2048
#define D_MODEL 1024
#define N_HEADS 16
#define HEAD_DIM 64
#define FFN_DIM 4096

typedef _Float16 halfx8 __attribute__((ext_vector_type(8)));
typedef _Float16 halfx4 __attribute__((ext_vector_type(4)));
typedef float floatx4 __attribute__((ext_vector_type(4)));

__device__ __forceinline__ void async_ld16(const _Float16* g, _Float16* l) {
  __builtin_amdgcn_global_load_lds(
      (const __attribute__((address_space(1))) unsigned int*)g,
      (__attribute__((address_space(3))) unsigned int*)l, 16, 0, 0);
}

// Fine-grained barrier: wait until <=N vector-mem ops outstanding, s_barrier.
template <int N> __device__ __forceinline__ void wait_barrier();
template <> __device__ __forceinline__ void wait_barrier<0>() {
  asm volatile("s_waitcnt vmcnt(0)\n\ts_barrier" ::: "memory");
}
template <> __device__ __forceinline__ void wait_barrier<3>() {
  asm volatile("s_waitcnt vmcnt(3)\n\ts_barrier" ::: "memory");
}
template <> __device__ __forceinline__ void wait_barrier<4>() {
  asm volatile("s_waitcnt vmcnt(4)\n\ts_barrier" ::: "memory");
}

// ---------------- LayerNorm (D=1024 fixed): one block per row, fp16 out ----
__global__ __launch_bounds__(256) void ln_h_kernel(
    const float* __restrict__ x, const float* __restrict__ g,
    const float* __restrict__ b, _Float16* __restrict__ y) {
  int row = blockIdx.x;
  const float* xr = x + (size_t)row * D_MODEL;
  _Float16* yr = y + (size_t)row * D_MODEL;
  int tid = threadIdx.x;
  int lid = tid & 63, wid = tid >> 6;
  __shared__ float red[8];

  float4 v = *(const float4*)&xr[tid * 4];
  float sum = v.x + v.y + v.z + v.w;
  for (int o = 32; o > 0; o >>= 1) sum += __shfl_down(sum, o, 64);
  if (lid == 0) red[wid] = sum;
  __syncthreads();
  if (tid == 0) { float t = 0; for (int i = 0; i < 4; i++) t += red[i]; red[0] = t; }
  __syncthreads();
  float mu = red[0] * (1.0f / D_MODEL);
  __syncthreads();

  float dx = v.x - mu, dy = v.y - mu, dz = v.z - mu, dw = v.w - mu;
  float vs = dx * dx + dy * dy + dz * dz + dw * dw;
  for (int o = 32; o > 0; o >>= 1) vs += __shfl_down(vs, o, 64);
  if (lid == 0) red[wid] = vs;
  __syncthreads();
  if (tid == 0) { float t = 0; for (int i = 0; i < 4; i++) t += red[i]; red[0] = t; }
  __syncthreads();
  float rstd = rsqrtf(red[0] * (1.0f / D_MODEL) + 1e-5f);

  float4 gv = *(const float4*)&g[tid * 4];
  float4 bv = *(const float4*)&b[tid * 4];
  halfx4 o;
  o[0] = (_Float16)(dx * rstd * gv.x + bv.x);
  o[1] = (_Float16)(dy * rstd * gv.y + bv.y);
  o[2] = (_Float16)(dz * rstd * gv.z + bv.z);
  o[3] = (_Float16)(dw * rstd * gv.w + bv.w);
  *(halfx4*)&yr[tid * 4] = o;
}

// ------- fused prep: all 6 weight transposes (fp32->fp16 [n][k]) + bias ----
__global__ __launch_bounds__(256) void prep_kernel(
    const float* __restrict__ wq, const float* __restrict__ wk,
    const float* __restrict__ wv, const float* __restrict__ wo,
    const float* __restrict__ w1, const float* __restrict__ w2,
    const float* __restrict__ bq, const float* __restrict__ bk,
    const float* __restrict__ bv, _Float16* __restrict__ Wqkvt,
    _Float16* __restrict__ Wot, _Float16* __restrict__ W1t,
    _Float16* __restrict__ W2t, float* __restrict__ bqkv) {
  int bId = blockIdx.x;
  int tid = threadIdx.x;
  if (bId >= 12288) {  // bias pack
    int i = (bId - 12288) * 256 + tid;
    if (i < 1024) bqkv[i] = bq[i];
    else if (i < 2048) bqkv[i] = bk[i - 1024];
    else bqkv[i] = bv[i - 2048];
    return;
  }
  const float* in; _Float16* outp; int K, N, t;
  if (bId < 1024)      { in = wq; outp = Wqkvt;                 K = 1024; N = 1024; t = bId; }
  else if (bId < 2048) { in = wk; outp = Wqkvt + 1024 * 1024;   K = 1024; N = 1024; t = bId - 1024; }
  else if (bId < 3072) { in = wv; outp = Wqkvt + 2 * 1024 * 1024; K = 1024; N = 1024; t = bId - 2048; }
  else if (bId < 4096) { in = wo; outp = Wot;                   K = 1024; N = 1024; t = bId - 3072; }
  else if (bId < 8192) { in = w1; outp = W1t;                   K = 1024; N = 4096; t = bId - 4096; }
  else                 { in = w2; outp = W2t;                   K = 4096; N = 1024; t = bId - 8192; }
  int ntn = N / 32;
  int tk = (t / ntn) * 32, tn = (t % ntn) * 32;

  __shared__ float tile[32][33];
  int r = tid >> 3, c = (tid & 7) * 4;
  float4 v = *(const float4*)&in[(size_t)(tk + r) * N + tn + c];
  tile[r][c] = v.x; tile[r][c + 1] = v.y; tile[r][c + 2] = v.z; tile[r][c + 3] = v.w;
  __syncthreads();
  halfx4 o;
  o[0] = (_Float16)tile[c][r];
  o[1] = (_Float16)tile[c + 1][r];
  o[2] = (_Float16)tile[c + 2][r];
  o[3] = (_Float16)tile[c + 3][r];
  *(halfx4*)&outp[(size_t)(tn + r) * K + tk + c] = o;
}

// ---------------- MFMA f16 GEMM: C = A(MxK) @ Bt^T + bias ----------------
// Ring-of-3 LDS buffers, 2-deep async prefetch, fine-grained vmcnt barrier.
// REP: diagnostic repetition (idempotent) to lift dur above rocprof top-5
// fill floor. Last-iter uses vmcnt(0) (tail-race fix).
template <int MODE, int BM, int BN, int REP>
__global__ __launch_bounds__(256) void hgemm_kernel(
    const _Float16* __restrict__ A, const _Float16* __restrict__ Bt,
    const float* __restrict__ bias, const float* __restrict__ res,
    float* __restrict__ Cf, _Float16* __restrict__ Ch,
    _Float16* __restrict__ Vtg, int M, int N, int K) {
  constexpr int TM = BM / 32;
  constexpr int TN = BN / 32;
  constexpr int AR = BM / 64;
  constexpr int BR = BN / 64;
  constexpr int L = AR + BR;
  __shared__ _Float16 As[3][BM][32];
  __shared__ _Float16 Bs[3][BN][32];
  const int tid = threadIdx.x;
  const int w = tid >> 6, lane = tid & 63;
  const int l16 = lane & 15, quad = lane >> 4;
  const int m0 = blockIdx.y * BM, n0 = blockIdx.x * BN;
  const int wm = (w >> 1) * (BM / 2), wn = (w & 1) * (BN / 2);

  floatx4 acc[TM][TN];

  const int srow = w * 16 + (lane >> 2);
  const int gg = (lane & 3) ^ ((srow >> 1) & 3);
  const _Float16* Agp = A + (size_t)(m0 + srow) * K + gg * 8;
  const _Float16* Bgp = Bt + (size_t)(n0 + srow) * K + gg * 8;

  const int colA = (quad ^ ((l16 >> 1) & 3)) * 8;

  const int NIT = K / 32;
#define HG_ISSUE(buf, k0)                                                     \
  {                                                                           \
    _Pragma("unroll") for (int i = 0; i < AR; i++)                            \
        async_ld16(Agp + (k0) + (size_t)i * 64 * K, &As[buf][i * 64 + w * 16][0]); \
    _Pragma("unroll") for (int i = 0; i < BR; i++)                            \
        async_ld16(Bgp + (k0) + (size_t)i * 64 * K, &Bs[buf][i * 64 + w * 16][0]); \
  }

  for (int rep = 0; rep < REP; rep++) {
    if (rep) __syncthreads();  // protect LDS reuse across reps
#pragma unroll
    for (int i = 0; i < TM; i++)
#pragma unroll
      for (int j = 0; j < TN; j++) acc[i][j] = (floatx4){0.f, 0.f, 0.f, 0.f};

    HG_ISSUE(0, 0)
    HG_ISSUE(1, 32)

    for (int it = 0; it < NIT; it++) {
      const int buf = it % 3;
      if (it + 1 < NIT) wait_barrier<L>();
      else wait_barrier<0>();  // tail: own-buf loads may be the only ones left
      if (it + 2 < NIT) HG_ISSUE((it + 2) % 3, (it + 2) * 32)
      halfx8 af[TM], bf[TN];
#pragma unroll
      for (int mt = 0; mt < TM; mt++)
        af[mt] = *(const halfx8*)&As[buf][wm + mt * 16 + l16][colA];
#pragma unroll
      for (int nt = 0; nt < TN; nt++)
        bf[nt] = *(const halfx8*)&Bs[buf][wn + nt * 16 + l16][colA];
#pragma unroll
      for (int mt = 0; mt < TM; mt++)
#pragma unroll
        for (int nt = 0; nt < TN; nt++)
          acc[mt][nt] = __builtin_amdgcn_mfma_f32_16x16x32_f16(af[mt], bf[nt], acc[mt][nt], 0, 0, 0);
    }
  }

#pragma unroll
  for (int mt = 0; mt < TM; mt++) {
    int row0 = m0 + wm + mt * 16 + quad * 4;
#pragma unroll
    for (int nt = 0; nt < TN; nt++) {
      int col = n0 + wn + nt * 16 + l16;
      float bv = bias[col];
      float vv[4];
#pragma unroll
      for (int r = 0; r < 4; r++) {
        float v = acc[mt][nt][r] + bv;
        if (MODE == 1) v = 0.5f * v * (1.0f + erff(v * 0.70710678118f));
        vv[r] = v;
      }
      if (MODE == 2) {
#pragma unroll
        for (int r = 0; r < 4; r++)
          Cf[(size_t)(row0 + r) * N + col] = vv[r] + res[(size_t)(row0 + r) * N + col];
      } else if (MODE == 3) {
        if (col < 2048) {
#pragma unroll
          for (int r = 0; r < 4; r++)
            Ch[(size_t)(row0 + r) * 2048 + col] = (_Float16)vv[r];
        } else {
          halfx4 pk;
#pragma unroll
          for (int r = 0; r < 4; r++) pk[r] = (_Float16)vv[r];
          *(halfx4*)&Vtg[(size_t)(col - 2048) * T_SEQ + row0] = pk;
        }
      } else {
#pragma unroll
        for (int r = 0; r < 4; r++)
          Ch[(size_t)(row0 + r) * N + col] = (_Float16)vv[r];
      }
    }
  }
}

// ---------------- Flash attention: MFMA f16, online softmax ----------------
#define LROW 72
template <int REP>
__global__ __launch_bounds__(256) void flash_attn_kernel(
    const _Float16* __restrict__ QK, const _Float16* __restrict__ Vtg,
    _Float16* __restrict__ out) {
  __shared__ _Float16 Ks[3][64][64];
  __shared__ _Float16 Vt[3][64][64];
  __shared__ _Float16 Ps[4][16][LROW];

  const int h = blockIdx.y;
  const int qt = 31 - blockIdx.x;  // LPT
  const int q0 = qt * 64;
  const int tid = threadIdx.x;
  const int w = tid >> 6;
  const int lane = tid & 63;
  const int l16 = lane & 15;
  const int quad = lane >> 4;

  const _Float16* Qg = QK + h * HEAD_DIM;
  const _Float16* Kg = QK + 1024 + h * HEAD_DIM;
  const _Float16* Vg = Vtg + (size_t)h * HEAD_DIM * T_SEQ;

  const _Float16* qp = Qg + (size_t)(q0 + w * 16 + l16) * 2048;
  halfx8 qa0 = *(const halfx8*)(qp + quad * 8);
  halfx8 qa1 = *(const halfx8*)(qp + 32 + quad * 8);

  const float scale2 = 0.18033688f;  // 0.125 * log2(e)
  const float slope2 = exp2f(-0.5f * (float)(h + 1)) * 1.44269504f;
  const int row_base = q0 + w * 16 + quad * 4;

  const int sr = w * 8 + (lane >> 3);
  const int gg = (lane & 7) ^ ((lane >> 3) & 7);
  const _Float16* Kp = Kg + (size_t)sr * 2048 + gg * 8;
  const _Float16* Vp = Vg + (size_t)sr * 2048 + gg * 8;

  const int m7 = l16 & 7;
  const int cK0 = (quad ^ m7) * 8;
  const int cK1 = cK0 ^ 32;
  const int cV0 = (quad ^ m7) * 8;
  const int cV1 = ((quad + 4) ^ m7) * 8;

#define FA_ISSUE(buf, k0)                                                      \
  {                                                                            \
    async_ld16(Kp + (size_t)(k0) * 2048, &Ks[buf][w * 8][0]);                  \
    async_ld16(Kp + (size_t)((k0) + 32) * 2048, &Ks[buf][32 + w * 8][0]);      \
    async_ld16(Vp + (k0), &Vt[buf][w * 8][0]);                                 \
    async_ld16(Vp + (size_t)32 * 2048 + (k0), &Vt[buf][32 + w * 8][0]);        \
  }

  float m_i[4], l_i[4];
  floatx4 o_acc[4];

  for (int rep = 0; rep < REP; rep++) {
    if (rep) __syncthreads();
#pragma unroll
    for (int r = 0; r < 4; r++) { m_i[r] = -INFINITY; l_i[r] = 0.f; }
#pragma unroll
    for (int c = 0; c < 4; c++) o_acc[c] = (floatx4){0.f, 0.f, 0.f, 0.f};

    FA_ISSUE(0, 0)
    if (qt >= 1) FA_ISSUE(1, 64)

    for (int t = 0; t <= qt; t++) {
      const int k0 = t * 64;
      const int buf = t % 3;
      if (t < qt) wait_barrier<4>();
      else wait_barrier<0>();  // tail-race fix (esp. qt==0 blocks)
      if (t + 2 <= qt) FA_ISSUE((t + 2) % 3, (t + 2) * 64)

      // ---- S = Q K^T
      float sc[4][4];
#pragma unroll
      for (int sub = 0; sub < 4; sub++) {
        const _Float16* kr = &Ks[buf][sub * 16 + l16][0];
        halfx8 b0 = *(const halfx8*)(kr + cK0);
        halfx8 b1 = *(const halfx8*)(kr + cK1);
        floatx4 acc = (floatx4){0.f, 0.f, 0.f, 0.f};
        acc = __builtin_amdgcn_mfma_f32_16x16x32_f16(qa0, b0, acc, 0, 0, 0);
        acc = __builtin_amdgcn_mfma_f32_16x16x32_f16(qa1, b1, acc, 0, 0, 0);
#pragma unroll
        for (int r = 0; r < 4; r++) sc[sub][r] = acc[r];
      }

      // ---- online softmax
      const bool diag = (t == qt);
#pragma unroll
      for (int r = 0; r < 4; r++) {
        const int rg = row_base + r;
        float mx = m_i[r];
#pragma unroll
        for (int sub = 0; sub < 4; sub++) {
          int cg = k0 + sub * 16 + l16;
          float s = sc[sub][r] * scale2 + slope2 * (float)(cg - rg);
          if (diag && cg > rg) s = -1e30f;
          sc[sub][r] = s;
          mx = fmaxf(mx, s);
        }
        mx = fmaxf(mx, __shfl_xor(mx, 1, 64));
        mx = fmaxf(mx, __shfl_xor(mx, 2, 64));
        mx = fmaxf(mx, __shfl_xor(mx, 4, 64));
        mx = fmaxf(mx, __shfl_xor(mx, 8, 64));
        float alpha = exp2f(m_i[r] - mx);
        m_i[r] = mx;
        float ls = 0.f;
#pragma unroll
        for (int sub = 0; sub < 4; sub++) {
          float p = exp2f(sc[sub][r] - mx);
          ls += p;
          Ps[w][quad * 4 + r][sub * 16 + l16] = (_Float16)p;
        }
        ls += __shfl_xor(ls, 1, 64);
        ls += __shfl_xor(ls, 2, 64);
        ls += __shfl_xor(ls, 4, 64);
        ls += __shfl_xor(ls, 8, 64);
        l_i[r] = l_i[r] * alpha + ls;
#pragma unroll
        for (int c = 0; c < 4; c++) o_acc[c][r] *= alpha;
      }

      // ---- O += P V
#pragma unroll
      for (int kh = 0; kh < 2; kh++) {
        halfx8 pa = *(const halfx8*)(&Ps[w][l16][kh * 32 + quad * 8]);
        const int cV = kh ? cV1 : cV0;
#pragma unroll
        for (int c = 0; c < 4; c++) {
          halfx8 vb = *(const halfx8*)(&Vt[buf][c * 16 + l16][cV]);
          o_acc[c] = __builtin_amdgcn_mfma_f32_16x16x32_f16(pa, vb, o_acc[c], 0, 0, 0);
        }
      }
    }
  }

#pragma unroll
  for (int c = 0; c < 4; c++)
#pragma unroll
    for (int r = 0; r < 4; r++)
      out[(size_t)(row_base + r) * D_MODEL + h * HEAD_DIM + c * 16 + l16] =
          (_Float16)(o_acc[c][r] / l_i[r]);
}

extern "C" void kernel_launch(void* const* d_in, const int* in_sizes, int n_in,
                              void* d_out, int out_size, void* d_ws, size_t ws_size,
                              hipStream_t stream) {
  const float* x   = (const float*)d_in[0];
  const float* wq  = (const float*)d_in[3];
  const float* bq  = (const float*)d_in[4];
  const float* wk  = (const float*)d_in[5];
  const float* bk  = (const float*)d_in[6];
  const float* wv  = (const float*)d_in[7];
  const float* bv  = (const float*)d_in[8];
  const float* wo  = (const float*)d_in[9];
  const float* bo  = (const float*)d_in[10];
  const float* w1  = (const float*)d_in[11];
  const float* b1  = (const float*)d_in[12];
  const float* w2  = (const float*)d_in[13];
  const float* b2  = (const float*)d_in[14];
  const float* g1  = (const float*)d_in[15];
  const float* be1 = (const float*)d_in[16];
  const float* g2  = (const float*)d_in[17];
  const float* be2 = (const float*)d_in[18];
  float* out = (float*)d_out;

  const size_t TD = (size_t)T_SEQ * D_MODEL;  // 2M
  char* p = (char*)d_ws;
  float*    x1    = (float*)p;     p += TD * 4;
  float*    bqkv  = (float*)p;     p += 4096 * 4;
  _Float16* xnh   = (_Float16*)p;  p += TD * 2;
  _Float16* QKh   = (_Float16*)p;  p += (size_t)2048 * 2048 * 2;
  _Float16* Vtg   = (_Float16*)p;  p += (size_t)1024 * 2048 * 2;
  _Float16* attnh = (_Float16*)p;  p += TD * 2;
  _Float16* hh    = (_Float16*)p;  p += (size_t)2048 * 4096 * 2;
  _Float16* Wqkvt = (_Float16*)p;  p += (size_t)3 * 1024 * 1024 * 2;
  _Float16* Wot   = (_Float16*)p;  p += (size_t)1024 * 1024 * 2;
  _Float16* W1t   = (_Float16*)p;  p += (size_t)1024 * 4096 * 2;
  _Float16* W2t   = (_Float16*)p;  p += (size_t)4096 * 1024 * 2;

  dim3 blk(256);

  prep_kernel<<<dim3(12300), blk, 0, stream>>>(wq, wk, wv, wo, w1, w2, bq, bk, bv,
                                               Wqkvt, Wot, W1t, W2t, bqkv);

  ln_h_kernel<<<T_SEQ, blk, 0, stream>>>(x, g1, be1, xnh);

  // fused QKV (REP=3 diagnostic)
  hgemm_kernel<3, 128, 128, 3><<<dim3(3072 / 128, T_SEQ / 128), blk, 0, stream>>>(
      xnh, Wqkvt, bqkv, nullptr, nullptr, QKh, Vtg, T_SEQ, 3072, 1024);

  flash_attn_kernel<3><<<dim3(T_SEQ / 64, N_HEADS), blk, 0, stream>>>(QKh, Vtg, attnh);

  // O-proj + residual(x) -> x1 (REP=3)
  hgemm_kernel<2, 64, 128, 3><<<dim3(1024 / 128, T_SEQ / 64), blk, 0, stream>>>(
      attnh, Wot, bo, x, x1, nullptr, nullptr, T_SEQ, 1024, 1024);

  ln_h_kernel<<<T_SEQ, blk, 0, stream>>>(x1, g2, be2, xnh);

  // FFN1 + GELU (REP=3)
  hgemm_kernel<1, 128, 128, 3><<<dim3(4096 / 128, T_SEQ / 128), blk, 0, stream>>>(
      xnh, W1t, b1, nullptr, nullptr, hh, nullptr, T_SEQ, 4096, 1024);

  // FFN2 + residual(x1) -> out (REP=3)
  hgemm_kernel<2, 64, 128, 3><<<dim3(1024 / 128, T_SEQ / 64), blk, 0, stream>>>(
      hh, W2t, b2, x1, out, nullptr, nullptr, T_SEQ, 1024, 4096);
}

// Round 8
// 572.344 us; speedup vs baseline: 1.5374x; 1.5374x over previous
//
#include <hip/hip_runtime.h>
#include <hip/hip_bf16.h>
#include <math.h>

#define T_SEQ 2048
#define D_MODEL 1024
#define N_HEADS 16
#define HEAD_DIM 64
#define FFN_DIM 4096

typedef _Float16 halfx8 __attribute__((ext_vector_type(8)));
typedef _Float16 halfx4 __attribute__((ext_vector_type(4)));
typedef float floatx4 __attribute__((ext_vector_type(4)));

__device__ __forceinline__ void async_ld16(const _Float16* g, _Float16* l) {
  __builtin_amdgcn_global_load_lds(
      (const __attribute__((address_space(1))) unsigned int*)g,
      (__attribute__((address_space(3))) unsigned int*)l, 16, 0, 0);
}

// Fine-grained barrier: wait until <=N vector-mem ops outstanding, s_barrier.
template <int N> __device__ __forceinline__ void wait_barrier();
template <> __device__ __forceinline__ void wait_barrier<0>() {
  asm volatile("s_waitcnt vmcnt(0)\n\ts_barrier" ::: "memory");
}
template <> __device__ __forceinline__ void wait_barrier<2>() {
  asm volatile("s_waitcnt vmcnt(2)\n\ts_barrier" ::: "memory");
}
template <> __device__ __forceinline__ void wait_barrier<3>() {
  asm volatile("s_waitcnt vmcnt(3)\n\ts_barrier" ::: "memory");
}
template <> __device__ __forceinline__ void wait_barrier<4>() {
  asm volatile("s_waitcnt vmcnt(4)\n\ts_barrier" ::: "memory");
}

// ---- fused prep: 6 weight transposes (fp32->fp16 [n][k]) + bias + LN1 ----
__global__ __launch_bounds__(256) void prep_ln_kernel(
    const float* __restrict__ wq, const float* __restrict__ wk,
    const float* __restrict__ wv, const float* __restrict__ wo,
    const float* __restrict__ w1, const float* __restrict__ w2,
    const float* __restrict__ bq, const float* __restrict__ bk,
    const float* __restrict__ bv, _Float16* __restrict__ Wqkvt,
    _Float16* __restrict__ Wot, _Float16* __restrict__ W1t,
    _Float16* __restrict__ W2t, float* __restrict__ bqkv,
    const float* __restrict__ x, const float* __restrict__ g1,
    const float* __restrict__ be1, _Float16* __restrict__ xnh) {
  int bId = blockIdx.x;
  int tid = threadIdx.x;
  if (bId >= 12300) {  // LayerNorm rows
    int row = bId - 12300;
    const float* xr = x + (size_t)row * D_MODEL;
    _Float16* yr = xnh + (size_t)row * D_MODEL;
    int lid = tid & 63, wid = tid >> 6;
    __shared__ float red[8];
    float4 v = *(const float4*)&xr[tid * 4];
    float sum = v.x + v.y + v.z + v.w;
    for (int o = 32; o > 0; o >>= 1) sum += __shfl_down(sum, o, 64);
    if (lid == 0) red[wid] = sum;
    __syncthreads();
    if (tid == 0) { float t = 0; for (int i = 0; i < 4; i++) t += red[i]; red[0] = t; }
    __syncthreads();
    float mu = red[0] * (1.0f / D_MODEL);
    __syncthreads();
    float dx = v.x - mu, dy = v.y - mu, dz = v.z - mu, dw = v.w - mu;
    float vs = dx * dx + dy * dy + dz * dz + dw * dw;
    for (int o = 32; o > 0; o >>= 1) vs += __shfl_down(vs, o, 64);
    if (lid == 0) red[wid] = vs;
    __syncthreads();
    if (tid == 0) { float t = 0; for (int i = 0; i < 4; i++) t += red[i]; red[0] = t; }
    __syncthreads();
    float rstd = rsqrtf(red[0] * (1.0f / D_MODEL) + 1e-5f);
    float4 gv = *(const float4*)&g1[tid * 4];
    float4 bv4 = *(const float4*)&be1[tid * 4];
    halfx4 o;
    o[0] = (_Float16)(dx * rstd * gv.x + bv4.x);
    o[1] = (_Float16)(dy * rstd * gv.y + bv4.y);
    o[2] = (_Float16)(dz * rstd * gv.z + bv4.z);
    o[3] = (_Float16)(dw * rstd * gv.w + bv4.w);
    *(halfx4*)&yr[tid * 4] = o;
    return;
  }
  if (bId >= 12288) {  // bias pack
    int i = (bId - 12288) * 256 + tid;
    if (i < 1024) bqkv[i] = bq[i];
    else if (i < 2048) bqkv[i] = bk[i - 1024];
    else bqkv[i] = bv[i - 2048];
    return;
  }
  const float* in; _Float16* outp; int K, N, t;
  if (bId < 1024)      { in = wq; outp = Wqkvt;                 K = 1024; N = 1024; t = bId; }
  else if (bId < 2048) { in = wk; outp = Wqkvt + 1024 * 1024;   K = 1024; N = 1024; t = bId - 1024; }
  else if (bId < 3072) { in = wv; outp = Wqkvt + 2 * 1024 * 1024; K = 1024; N = 1024; t = bId - 2048; }
  else if (bId < 4096) { in = wo; outp = Wot;                   K = 1024; N = 1024; t = bId - 3072; }
  else if (bId < 8192) { in = w1; outp = W1t;                   K = 1024; N = 4096; t = bId - 4096; }
  else                 { in = w2; outp = W2t;                   K = 4096; N = 1024; t = bId - 8192; }
  int ntn = N / 32;
  int tk = (t / ntn) * 32, tn = (t % ntn) * 32;

  __shared__ float tile[32][33];
  int r = tid >> 3, c = (tid & 7) * 4;
  float4 v = *(const float4*)&in[(size_t)(tk + r) * N + tn + c];
  tile[r][c] = v.x; tile[r][c + 1] = v.y; tile[r][c + 2] = v.z; tile[r][c + 3] = v.w;
  __syncthreads();
  halfx4 o;
  o[0] = (_Float16)tile[c][r];
  o[1] = (_Float16)tile[c + 1][r];
  o[2] = (_Float16)tile[c + 2][r];
  o[3] = (_Float16)tile[c + 3][r];
  *(halfx4*)&outp[(size_t)(tn + r) * K + tk + c] = o;
}

// ---------------- LayerNorm (standalone, for LN2) ----------------
__global__ __launch_bounds__(256) void ln_h_kernel(
    const float* __restrict__ x, const float* __restrict__ g,
    const float* __restrict__ b, _Float16* __restrict__ y) {
  int row = blockIdx.x;
  const float* xr = x + (size_t)row * D_MODEL;
  _Float16* yr = y + (size_t)row * D_MODEL;
  int tid = threadIdx.x;
  int lid = tid & 63, wid = tid >> 6;
  __shared__ float red[8];

  float4 v = *(const float4*)&xr[tid * 4];
  float sum = v.x + v.y + v.z + v.w;
  for (int o = 32; o > 0; o >>= 1) sum += __shfl_down(sum, o, 64);
  if (lid == 0) red[wid] = sum;
  __syncthreads();
  if (tid == 0) { float t = 0; for (int i = 0; i < 4; i++) t += red[i]; red[0] = t; }
  __syncthreads();
  float mu = red[0] * (1.0f / D_MODEL);
  __syncthreads();

  float dx = v.x - mu, dy = v.y - mu, dz = v.z - mu, dw = v.w - mu;
  float vs = dx * dx + dy * dy + dz * dz + dw * dw;
  for (int o = 32; o > 0; o >>= 1) vs += __shfl_down(vs, o, 64);
  if (lid == 0) red[wid] = vs;
  __syncthreads();
  if (tid == 0) { float t = 0; for (int i = 0; i < 4; i++) t += red[i]; red[0] = t; }
  __syncthreads();
  float rstd = rsqrtf(red[0] * (1.0f / D_MODEL) + 1e-5f);

  float4 gv = *(const float4*)&g[tid * 4];
  float4 bv = *(const float4*)&b[tid * 4];
  halfx4 o;
  o[0] = (_Float16)(dx * rstd * gv.x + bv.x);
  o[1] = (_Float16)(dy * rstd * gv.y + bv.y);
  o[2] = (_Float16)(dz * rstd * gv.z + bv.z);
  o[3] = (_Float16)(dw * rstd * gv.w + bv.w);
  *(halfx4*)&yr[tid * 4] = o;
}

// ---------------- MFMA f16 GEMM (ring-3, 2-deep prefetch) ----------------
template <int MODE, int BM, int BN>
__global__ __launch_bounds__(256) void hgemm_kernel(
    const _Float16* __restrict__ A, const _Float16* __restrict__ Bt,
    const float* __restrict__ bias, const float* __restrict__ res,
    float* __restrict__ Cf, _Float16* __restrict__ Ch,
    _Float16* __restrict__ Vtg, int M, int N, int K) {
  constexpr int TM = BM / 32;
  constexpr int TN = BN / 32;
  constexpr int AR = BM / 64;
  constexpr int BR = BN / 64;
  constexpr int L = AR + BR;
  __shared__ _Float16 As[3][BM][32];
  __shared__ _Float16 Bs[3][BN][32];
  const int tid = threadIdx.x;
  const int w = tid >> 6, lane = tid & 63;
  const int l16 = lane & 15, quad = lane >> 4;
  const int m0 = blockIdx.y * BM, n0 = blockIdx.x * BN;
  const int wm = (w >> 1) * (BM / 2), wn = (w & 1) * (BN / 2);

  floatx4 acc[TM][TN];
#pragma unroll
  for (int i = 0; i < TM; i++)
#pragma unroll
    for (int j = 0; j < TN; j++) acc[i][j] = (floatx4){0.f, 0.f, 0.f, 0.f};

  const int srow = w * 16 + (lane >> 2);
  const int gg = (lane & 3) ^ ((srow >> 1) & 3);
  const _Float16* Agp = A + (size_t)(m0 + srow) * K + gg * 8;
  const _Float16* Bgp = Bt + (size_t)(n0 + srow) * K + gg * 8;

  const int colA = (quad ^ ((l16 >> 1) & 3)) * 8;

  const int NIT = K / 32;
#define HG_ISSUE(buf, k0)                                                     \
  {                                                                           \
    _Pragma("unroll") for (int i = 0; i < AR; i++)                            \
        async_ld16(Agp + (k0) + (size_t)i * 64 * K, &As[buf][i * 64 + w * 16][0]); \
    _Pragma("unroll") for (int i = 0; i < BR; i++)                            \
        async_ld16(Bgp + (k0) + (size_t)i * 64 * K, &Bs[buf][i * 64 + w * 16][0]); \
  }
  HG_ISSUE(0, 0)
  HG_ISSUE(1, 32)

  for (int it = 0; it < NIT; it++) {
    const int buf = it % 3;
    if (it + 1 < NIT) wait_barrier<L>();
    else wait_barrier<0>();  // tail
    if (it + 2 < NIT) HG_ISSUE((it + 2) % 3, (it + 2) * 32)
    halfx8 af[TM], bf[TN];
#pragma unroll
    for (int mt = 0; mt < TM; mt++)
      af[mt] = *(const halfx8*)&As[buf][wm + mt * 16 + l16][colA];
#pragma unroll
    for (int nt = 0; nt < TN; nt++)
      bf[nt] = *(const halfx8*)&Bs[buf][wn + nt * 16 + l16][colA];
#pragma unroll
    for (int mt = 0; mt < TM; mt++)
#pragma unroll
      for (int nt = 0; nt < TN; nt++)
        acc[mt][nt] = __builtin_amdgcn_mfma_f32_16x16x32_f16(af[mt], bf[nt], acc[mt][nt], 0, 0, 0);
  }

#pragma unroll
  for (int mt = 0; mt < TM; mt++) {
    int row0 = m0 + wm + mt * 16 + quad * 4;
#pragma unroll
    for (int nt = 0; nt < TN; nt++) {
      int col = n0 + wn + nt * 16 + l16;
      float bv = bias[col];
      float vv[4];
#pragma unroll
      for (int r = 0; r < 4; r++) {
        float v = acc[mt][nt][r] + bv;
        if (MODE == 1) v = 0.5f * v * (1.0f + erff(v * 0.70710678118f));
        vv[r] = v;
      }
      if (MODE == 2) {
#pragma unroll
        for (int r = 0; r < 4; r++)
          Cf[(size_t)(row0 + r) * N + col] = vv[r] + res[(size_t)(row0 + r) * N + col];
      } else if (MODE == 3) {
        if (col < 2048) {
#pragma unroll
          for (int r = 0; r < 4; r++)
            Ch[(size_t)(row0 + r) * 2048 + col] = (_Float16)vv[r];
        } else {
          halfx4 pk;
#pragma unroll
          for (int r = 0; r < 4; r++) pk[r] = (_Float16)vv[r];
          *(halfx4*)&Vtg[(size_t)(col - 2048) * T_SEQ + row0] = pk;
        }
      } else {
#pragma unroll
        for (int r = 0; r < 4; r++)
          Ch[(size_t)(row0 + r) * N + col] = (_Float16)vv[r];
      }
    }
  }
}

// ---------------- Flash attention: ring-2 K/V, 3 blocks/CU ----------------
#define LROW 72
__global__ __launch_bounds__(256) void flash_attn_kernel(
    const _Float16* __restrict__ QK, const _Float16* __restrict__ Vtg,
    _Float16* __restrict__ out) {
  __shared__ _Float16 Ks[2][64][64];
  __shared__ _Float16 Vt[2][64][64];
  __shared__ _Float16 Ps[4][16][LROW];

  const int h = blockIdx.y;
  const int qt = 31 - blockIdx.x;  // LPT
  const int q0 = qt * 64;
  const int tid = threadIdx.x;
  const int w = tid >> 6;
  const int lane = tid & 63;
  const int l16 = lane & 15;
  const int quad = lane >> 4;

  const _Float16* Qg = QK + h * HEAD_DIM;
  const _Float16* Kg = QK + 1024 + h * HEAD_DIM;
  const _Float16* Vg = Vtg + (size_t)h * HEAD_DIM * T_SEQ;

  const _Float16* qp = Qg + (size_t)(q0 + w * 16 + l16) * 2048;
  halfx8 qa0 = *(const halfx8*)(qp + quad * 8);
  halfx8 qa1 = *(const halfx8*)(qp + 32 + quad * 8);

  const float scale2 = 0.18033688f;  // 0.125 * log2(e)
  const float slope2 = exp2f(-0.5f * (float)(h + 1)) * 1.44269504f;
  const int row_base = q0 + w * 16 + quad * 4;

  const int sr = w * 8 + (lane >> 3);
  const int gg = (lane & 7) ^ ((lane >> 3) & 7);
  const _Float16* Kp = Kg + (size_t)sr * 2048 + gg * 8;
  const _Float16* Vp = Vg + (size_t)sr * 2048 + gg * 8;

  const int m7 = l16 & 7;
  const int cK0 = (quad ^ m7) * 8;
  const int cK1 = cK0 ^ 32;
  const int cV0 = (quad ^ m7) * 8;
  const int cV1 = ((quad + 4) ^ m7) * 8;

#define FA_ISSUE(buf, k0)                                                      \
  {                                                                            \
    async_ld16(Kp + (size_t)(k0) * 2048, &Ks[buf][w * 8][0]);                  \
    async_ld16(Kp + (size_t)((k0) + 32) * 2048, &Ks[buf][32 + w * 8][0]);      \
    async_ld16(Vp + (k0), &Vt[buf][w * 8][0]);                                 \
    async_ld16(Vp + (size_t)32 * 2048 + (k0), &Vt[buf][32 + w * 8][0]);        \
  }

  float m_i[4], l_i[4];
  floatx4 o_acc[4];
#pragma unroll
  for (int r = 0; r < 4; r++) { m_i[r] = -INFINITY; l_i[r] = 0.f; }
#pragma unroll
  for (int c = 0; c < 4; c++) o_acc[c] = (floatx4){0.f, 0.f, 0.f, 0.f};

  FA_ISSUE(0, 0)

  for (int t = 0; t <= qt; t++) {
    const int k0 = t * 64;
    const int buf = t & 1;
    // Loads for tile t were issued one full tile of compute ago -> cheap.
    wait_barrier<0>();
    if (t < qt) FA_ISSUE(buf ^ 1, k0 + 64)

    // ---- S = Q K^T
    float sc[4][4];
#pragma unroll
    for (int sub = 0; sub < 4; sub++) {
      const _Float16* kr = &Ks[buf][sub * 16 + l16][0];
      halfx8 b0 = *(const halfx8*)(kr + cK0);
      halfx8 b1 = *(const halfx8*)(kr + cK1);
      floatx4 acc = (floatx4){0.f, 0.f, 0.f, 0.f};
      acc = __builtin_amdgcn_mfma_f32_16x16x32_f16(qa0, b0, acc, 0, 0, 0);
      acc = __builtin_amdgcn_mfma_f32_16x16x32_f16(qa1, b1, acc, 0, 0, 0);
#pragma unroll
      for (int r = 0; r < 4; r++) sc[sub][r] = acc[r];
    }

    // ---- online softmax (stage-outer shuffles for 4-row ILP)
    const bool diag = (t == qt);
    float mx[4];
#pragma unroll
    for (int r = 0; r < 4; r++) {
      const int rg = row_base + r;
      float ab = slope2 * (float)(k0 + l16 - rg);  // sub term added below
      mx[r] = m_i[r];
#pragma unroll
      for (int sub = 0; sub < 4; sub++) {
        float s = sc[sub][r] * scale2 + (ab + slope2 * (float)(sub * 16));
        if (diag && (k0 + sub * 16 + l16) > rg) s = -1e30f;
        sc[sub][r] = s;
        mx[r] = fmaxf(mx[r], s);
      }
    }
#pragma unroll
    for (int st = 1; st <= 8; st <<= 1)
#pragma unroll
      for (int r = 0; r < 4; r++) mx[r] = fmaxf(mx[r], __shfl_xor(mx[r], st, 64));

    float ls[4], alpha[4];
#pragma unroll
    for (int r = 0; r < 4; r++) {
      alpha[r] = exp2f(m_i[r] - mx[r]);
      m_i[r] = mx[r];
      float l = 0.f;
#pragma unroll
      for (int sub = 0; sub < 4; sub++) {
        float p = exp2f(sc[sub][r] - mx[r]);
        l += p;
        Ps[w][quad * 4 + r][sub * 16 + l16] = (_Float16)p;
      }
      ls[r] = l;
    }
#pragma unroll
    for (int st = 1; st <= 8; st <<= 1)
#pragma unroll
      for (int r = 0; r < 4; r++) ls[r] += __shfl_xor(ls[r], st, 64);
#pragma unroll
    for (int r = 0; r < 4; r++) {
      l_i[r] = l_i[r] * alpha[r] + ls[r];
#pragma unroll
      for (int c = 0; c < 4; c++) o_acc[c][r] *= alpha[r];
    }

    // ---- O += P V
#pragma unroll
    for (int kh = 0; kh < 2; kh++) {
      halfx8 pa = *(const halfx8*)(&Ps[w][l16][kh * 32 + quad * 8]);
      const int cV = kh ? cV1 : cV0;
#pragma unroll
      for (int c = 0; c < 4; c++) {
        halfx8 vb = *(const halfx8*)(&Vt[buf][c * 16 + l16][cV]);
        o_acc[c] = __builtin_amdgcn_mfma_f32_16x16x32_f16(pa, vb, o_acc[c], 0, 0, 0);
      }
    }
  }

#pragma unroll
  for (int c = 0; c < 4; c++)
#pragma unroll
    for (int r = 0; r < 4; r++)
      out[(size_t)(row_base + r) * D_MODEL + h * HEAD_DIM + c * 16 + l16] =
          (_Float16)(o_acc[c][r] / l_i[r]);
}

extern "C" void kernel_launch(void* const* d_in, const int* in_sizes, int n_in,
                              void* d_out, int out_size, void* d_ws, size_t ws_size,
                              hipStream_t stream) {
  const float* x   = (const float*)d_in[0];
  const float* wq  = (const float*)d_in[3];
  const float* bq  = (const float*)d_in[4];
  const float* wk  = (const float*)d_in[5];
  const float* bk  = (const float*)d_in[6];
  const float* wv  = (const float*)d_in[7];
  const float* bv  = (const float*)d_in[8];
  const float* wo  = (const float*)d_in[9];
  const float* bo  = (const float*)d_in[10];
  const float* w1  = (const float*)d_in[11];
  const float* b1  = (const float*)d_in[12];
  const float* w2  = (const float*)d_in[13];
  const float* b2  = (const float*)d_in[14];
  const float* g1  = (const float*)d_in[15];
  const float* be1 = (const float*)d_in[16];
  const float* g2  = (const float*)d_in[17];
  const float* be2 = (const float*)d_in[18];
  float* out = (float*)d_out;

  const size_t TD = (size_t)T_SEQ * D_MODEL;  // 2M
  char* p = (char*)d_ws;
  float*    x1    = (float*)p;     p += TD * 4;
  float*    bqkv  = (float*)p;     p += 4096 * 4;
  _Float16* xnh   = (_Float16*)p;  p += TD * 2;
  _Float16* QKh   = (_Float16*)p;  p += (size_t)2048 * 2048 * 2;
  _Float16* Vtg   = (_Float16*)p;  p += (size_t)1024 * 2048 * 2;
  _Float16* attnh = (_Float16*)p;  p += TD * 2;
  _Float16* hh    = (_Float16*)p;  p += (size_t)2048 * 4096 * 2;
  _Float16* Wqkvt = (_Float16*)p;  p += (size_t)3 * 1024 * 1024 * 2;
  _Float16* Wot   = (_Float16*)p;  p += (size_t)1024 * 1024 * 2;
  _Float16* W1t   = (_Float16*)p;  p += (size_t)1024 * 4096 * 2;
  _Float16* W2t   = (_Float16*)p;  p += (size_t)4096 * 1024 * 2;

  dim3 blk(256);

  // prep (weights/bias) + LN1 fused
  prep_ln_kernel<<<dim3(12300 + T_SEQ), blk, 0, stream>>>(
      wq, wk, wv, wo, w1, w2, bq, bk, bv, Wqkvt, Wot, W1t, W2t, bqkv,
      x, g1, be1, xnh);

  // fused QKV: Q,K row-major [2048][2048]; V^T [1024][2048]. 384 blocks.
  hgemm_kernel<3, 128, 128><<<dim3(3072 / 128, T_SEQ / 128), blk, 0, stream>>>(
      xnh, Wqkvt, bqkv, nullptr, nullptr, QKh, Vtg, T_SEQ, 3072, 1024);

  flash_attn_kernel<<<dim3(T_SEQ / 64, N_HEADS), blk, 0, stream>>>(QKh, Vtg, attnh);

  // O-proj + residual(x) -> x1 (fp32). 512 blocks.
  hgemm_kernel<2, 64, 64><<<dim3(1024 / 64, T_SEQ / 64), blk, 0, stream>>>(
      attnh, Wot, bo, x, x1, nullptr, nullptr, T_SEQ, 1024, 1024);

  ln_h_kernel<<<T_SEQ, blk, 0, stream>>>(x1, g2, be2, xnh);

  // FFN1 + GELU -> fp16. 512 blocks.
  hgemm_kernel<1, 128, 128><<<dim3(4096 / 128, T_SEQ / 128), blk, 0, stream>>>(
      xnh, W1t, b1, nullptr, nullptr, hh, nullptr, T_SEQ, 4096, 1024);

  // FFN2 + residual(x1) -> out (fp32). 512 blocks, K=4096.
  hgemm_kernel<2, 64, 64><<<dim3(1024 / 64, T_SEQ / 64), blk, 0, stream>>>(
      hh, W2t, b2, x1, out, nullptr, nullptr, T_SEQ, 1024, 4096);
}

// Round 10
// 563.078 us; speedup vs baseline: 1.5627x; 1.0165x over previous
//
#include <hip/hip_runtime.h>
#include <hip/hip_bf16.h>
#include <math.h>

#define T_SEQ 2048
#define D_MODEL 1024
#define N_HEADS 16
#define HEAD_DIM 64
#define FFN_DIM 4096

typedef _Float16 halfx8 __attribute__((ext_vector_type(8)));
typedef _Float16 halfx4 __attribute__((ext_vector_type(4)));
typedef float floatx4 __attribute__((ext_vector_type(4)));

__device__ __forceinline__ void async_ld16(const _Float16* g, _Float16* l) {
  __builtin_amdgcn_global_load_lds(
      (const __attribute__((address_space(1))) unsigned int*)g,
      (__attribute__((address_space(3))) unsigned int*)l, 16, 0, 0);
}

// Fine-grained barrier: wait until <=N vector-mem ops outstanding, s_barrier.
template <int N> __device__ __forceinline__ void wait_barrier();
template <> __device__ __forceinline__ void wait_barrier<0>() {
  asm volatile("s_waitcnt vmcnt(0)\n\ts_barrier" ::: "memory");
}
template <> __device__ __forceinline__ void wait_barrier<2>() {
  asm volatile("s_waitcnt vmcnt(2)\n\ts_barrier" ::: "memory");
}
template <> __device__ __forceinline__ void wait_barrier<3>() {
  asm volatile("s_waitcnt vmcnt(3)\n\ts_barrier" ::: "memory");
}
template <> __device__ __forceinline__ void wait_barrier<4>() {
  asm volatile("s_waitcnt vmcnt(4)\n\ts_barrier" ::: "memory");
}

// DPP 16-lane rotate-reduce step: v = OP(v, row_ror:<CTRL>(v)).
// Our reduction groups (fixed quad = lanes 16q..16q+15) match DPP rows.
#define DPP_STEP(v, CTRL, OP)                                                 \
  {                                                                           \
    float _t = __int_as_float(__builtin_amdgcn_update_dpp(                    \
        0, __float_as_int(v), CTRL, 0xF, 0xF, true));                         \
    (v) = OP((v), _t);                                                        \
  }
#define OP_MAXF(a, b) fmaxf((a), (b))
#define OP_ADDF(a, b) ((a) + (b))

// ---- fused prep: 6 weight transposes (fp32->fp16 [n][k]) + bias + LN1 ----
__global__ __launch_bounds__(256) void prep_ln_kernel(
    const float* __restrict__ wq, const float* __restrict__ wk,
    const float* __restrict__ wv, const float* __restrict__ wo,
    const float* __restrict__ w1, const float* __restrict__ w2,
    const float* __restrict__ bq, const float* __restrict__ bk,
    const float* __restrict__ bv, _Float16* __restrict__ Wqkvt,
    _Float16* __restrict__ Wot, _Float16* __restrict__ W1t,
    _Float16* __restrict__ W2t, float* __restrict__ bqkv,
    const float* __restrict__ x, const float* __restrict__ g1,
    const float* __restrict__ be1, _Float16* __restrict__ xnh) {
  int bId = blockIdx.x;
  int tid = threadIdx.x;
  if (bId >= 12300) {  // LayerNorm rows
    int row = bId - 12300;
    const float* xr = x + (size_t)row * D_MODEL;
    _Float16* yr = xnh + (size_t)row * D_MODEL;
    int lid = tid & 63, wid = tid >> 6;
    __shared__ float red[8];
    float4 v = *(const float4*)&xr[tid * 4];
    float sum = v.x + v.y + v.z + v.w;
    for (int o = 32; o > 0; o >>= 1) sum += __shfl_down(sum, o, 64);
    if (lid == 0) red[wid] = sum;
    __syncthreads();
    if (tid == 0) { float t = 0; for (int i = 0; i < 4; i++) t += red[i]; red[0] = t; }
    __syncthreads();
    float mu = red[0] * (1.0f / D_MODEL);
    __syncthreads();
    float dx = v.x - mu, dy = v.y - mu, dz = v.z - mu, dw = v.w - mu;
    float vs = dx * dx + dy * dy + dz * dz + dw * dw;
    for (int o = 32; o > 0; o >>= 1) vs += __shfl_down(vs, o, 64);
    if (lid == 0) red[wid] = vs;
    __syncthreads();
    if (tid == 0) { float t = 0; for (int i = 0; i < 4; i++) t += red[i]; red[0] = t; }
    __syncthreads();
    float rstd = rsqrtf(red[0] * (1.0f / D_MODEL) + 1e-5f);
    float4 gv = *(const float4*)&g1[tid * 4];
    float4 bv4 = *(const float4*)&be1[tid * 4];
    halfx4 o;
    o[0] = (_Float16)(dx * rstd * gv.x + bv4.x);
    o[1] = (_Float16)(dy * rstd * gv.y + bv4.y);
    o[2] = (_Float16)(dz * rstd * gv.z + bv4.z);
    o[3] = (_Float16)(dw * rstd * gv.w + bv4.w);
    *(halfx4*)&yr[tid * 4] = o;
    return;
  }
  if (bId >= 12288) {  // bias pack
    int i = (bId - 12288) * 256 + tid;
    if (i < 1024) bqkv[i] = bq[i];
    else if (i < 2048) bqkv[i] = bk[i - 1024];
    else bqkv[i] = bv[i - 2048];
    return;
  }
  const float* in; _Float16* outp; int K, N, t;
  if (bId < 1024)      { in = wq; outp = Wqkvt;                 K = 1024; N = 1024; t = bId; }
  else if (bId < 2048) { in = wk; outp = Wqkvt + 1024 * 1024;   K = 1024; N = 1024; t = bId - 1024; }
  else if (bId < 3072) { in = wv; outp = Wqkvt + 2 * 1024 * 1024; K = 1024; N = 1024; t = bId - 2048; }
  else if (bId < 4096) { in = wo; outp = Wot;                   K = 1024; N = 1024; t = bId - 3072; }
  else if (bId < 8192) { in = w1; outp = W1t;                   K = 1024; N = 4096; t = bId - 4096; }
  else                 { in = w2; outp = W2t;                   K = 4096; N = 1024; t = bId - 8192; }
  int ntn = N / 32;
  int tk = (t / ntn) * 32, tn = (t % ntn) * 32;

  __shared__ float tile[32][33];
  int r = tid >> 3, c = (tid & 7) * 4;
  float4 v = *(const float4*)&in[(size_t)(tk + r) * N + tn + c];
  tile[r][c] = v.x; tile[r][c + 1] = v.y; tile[r][c + 2] = v.z; tile[r][c + 3] = v.w;
  __syncthreads();
  halfx4 o;
  o[0] = (_Float16)tile[c][r];
  o[1] = (_Float16)tile[c + 1][r];
  o[2] = (_Float16)tile[c + 2][r];
  o[3] = (_Float16)tile[c + 3][r];
  *(halfx4*)&outp[(size_t)(tn + r) * K + tk + c] = o;
}

// ---------------- LayerNorm (standalone, for LN2) ----------------
__global__ __launch_bounds__(256) void ln_h_kernel(
    const float* __restrict__ x, const float* __restrict__ g,
    const float* __restrict__ b, _Float16* __restrict__ y) {
  int row = blockIdx.x;
  const float* xr = x + (size_t)row * D_MODEL;
  _Float16* yr = y + (size_t)row * D_MODEL;
  int tid = threadIdx.x;
  int lid = tid & 63, wid = tid >> 6;
  __shared__ float red[8];

  float4 v = *(const float4*)&xr[tid * 4];
  float sum = v.x + v.y + v.z + v.w;
  for (int o = 32; o > 0; o >>= 1) sum += __shfl_down(sum, o, 64);
  if (lid == 0) red[wid] = sum;
  __syncthreads();
  if (tid == 0) { float t = 0; for (int i = 0; i < 4; i++) t += red[i]; red[0] = t; }
  __syncthreads();
  float mu = red[0] * (1.0f / D_MODEL);
  __syncthreads();

  float dx = v.x - mu, dy = v.y - mu, dz = v.z - mu, dw = v.w - mu;
  float vs = dx * dx + dy * dy + dz * dz + dw * dw;
  for (int o = 32; o > 0; o >>= 1) vs += __shfl_down(vs, o, 64);
  if (lid == 0) red[wid] = vs;
  __syncthreads();
  if (tid == 0) { float t = 0; for (int i = 0; i < 4; i++) t += red[i]; red[0] = t; }
  __syncthreads();
  float rstd = rsqrtf(red[0] * (1.0f / D_MODEL) + 1e-5f);

  float4 gv = *(const float4*)&g[tid * 4];
  float4 bv = *(const float4*)&b[tid * 4];
  halfx4 o;
  o[0] = (_Float16)(dx * rstd * gv.x + bv.x);
  o[1] = (_Float16)(dy * rstd * gv.y + bv.y);
  o[2] = (_Float16)(dz * rstd * gv.z + bv.z);
  o[3] = (_Float16)(dw * rstd * gv.w + bv.w);
  *(halfx4*)&yr[tid * 4] = o;
}

// ---------------- MFMA f16 GEMM (ring-3, 2-deep prefetch) ----------------
template <int MODE, int BM, int BN>
__global__ __launch_bounds__(256) void hgemm_kernel(
    const _Float16* __restrict__ A, const _Float16* __restrict__ Bt,
    const float* __restrict__ bias, const float* __restrict__ res,
    float* __restrict__ Cf, _Float16* __restrict__ Ch,
    _Float16* __restrict__ Vtg, int M, int N, int K) {
  constexpr int TM = BM / 32;
  constexpr int TN = BN / 32;
  constexpr int AR = BM / 64;
  constexpr int BR = BN / 64;
  constexpr int L = AR + BR;
  __shared__ _Float16 As[3][BM][32];
  __shared__ _Float16 Bs[3][BN][32];
  const int tid = threadIdx.x;
  const int w = tid >> 6, lane = tid & 63;
  const int l16 = lane & 15, quad = lane >> 4;
  const int m0 = blockIdx.y * BM, n0 = blockIdx.x * BN;
  const int wm = (w >> 1) * (BM / 2), wn = (w & 1) * (BN / 2);

  floatx4 acc[TM][TN];
#pragma unroll
  for (int i = 0; i < TM; i++)
#pragma unroll
    for (int j = 0; j < TN; j++) acc[i][j] = (floatx4){0.f, 0.f, 0.f, 0.f};

  const int srow = w * 16 + (lane >> 2);
  const int gg = (lane & 3) ^ ((srow >> 1) & 3);
  const _Float16* Agp = A + (size_t)(m0 + srow) * K + gg * 8;
  const _Float16* Bgp = Bt + (size_t)(n0 + srow) * K + gg * 8;

  const int colA = (quad ^ ((l16 >> 1) & 3)) * 8;

  const int NIT = K / 32;
#define HG_ISSUE(buf, k0)                                                     \
  {                                                                           \
    _Pragma("unroll") for (int i = 0; i < AR; i++)                            \
        async_ld16(Agp + (k0) + (size_t)i * 64 * K, &As[buf][i * 64 + w * 16][0]); \
    _Pragma("unroll") for (int i = 0; i < BR; i++)                            \
        async_ld16(Bgp + (k0) + (size_t)i * 64 * K, &Bs[buf][i * 64 + w * 16][0]); \
  }
  HG_ISSUE(0, 0)
  HG_ISSUE(1, 32)

  for (int it = 0; it < NIT; it++) {
    const int buf = it % 3;
    if (it + 1 < NIT) wait_barrier<L>();
    else wait_barrier<0>();  // tail
    if (it + 2 < NIT) HG_ISSUE((it + 2) % 3, (it + 2) * 32)
    halfx8 af[TM], bf[TN];
#pragma unroll
    for (int mt = 0; mt < TM; mt++)
      af[mt] = *(const halfx8*)&As[buf][wm + mt * 16 + l16][colA];
#pragma unroll
    for (int nt = 0; nt < TN; nt++)
      bf[nt] = *(const halfx8*)&Bs[buf][wn + nt * 16 + l16][colA];
#pragma unroll
    for (int mt = 0; mt < TM; mt++)
#pragma unroll
      for (int nt = 0; nt < TN; nt++)
        acc[mt][nt] = __builtin_amdgcn_mfma_f32_16x16x32_f16(af[mt], bf[nt], acc[mt][nt], 0, 0, 0);
  }

#pragma unroll
  for (int mt = 0; mt < TM; mt++) {
    int row0 = m0 + wm + mt * 16 + quad * 4;
#pragma unroll
    for (int nt = 0; nt < TN; nt++) {
      int col = n0 + wn + nt * 16 + l16;
      float bv = bias[col];
      float vv[4];
#pragma unroll
      for (int r = 0; r < 4; r++) {
        float v = acc[mt][nt][r] + bv;
        if (MODE == 1) v = 0.5f * v * (1.0f + erff(v * 0.70710678118f));
        vv[r] = v;
      }
      if (MODE == 2) {
#pragma unroll
        for (int r = 0; r < 4; r++)
          Cf[(size_t)(row0 + r) * N + col] = vv[r] + res[(size_t)(row0 + r) * N + col];
      } else if (MODE == 3) {
        if (col < 2048) {
#pragma unroll
          for (int r = 0; r < 4; r++)
            Ch[(size_t)(row0 + r) * 2048 + col] = (_Float16)vv[r];
        } else {
          halfx4 pk;
#pragma unroll
          for (int r = 0; r < 4; r++) pk[r] = (_Float16)vv[r];
          *(halfx4*)&Vtg[(size_t)(col - 2048) * T_SEQ + row0] = pk;
        }
      } else {
#pragma unroll
        for (int r = 0; r < 4; r++)
          Ch[(size_t)(row0 + r) * N + col] = (_Float16)vv[r];
      }
    }
  }
}

// ---------------- Flash attention: ring-2 K/V, DPP reductions ----------------
#define LROW 72
__global__ __launch_bounds__(256) void flash_attn_kernel(
    const _Float16* __restrict__ QK, const _Float16* __restrict__ Vtg,
    _Float16* __restrict__ out) {
  __shared__ _Float16 Ks[2][64][64];
  __shared__ _Float16 Vt[2][64][64];
  __shared__ _Float16 Ps[4][16][LROW];

  const int h = blockIdx.y;
  const int qt = 31 - blockIdx.x;  // LPT
  const int q0 = qt * 64;
  const int tid = threadIdx.x;
  const int w = tid >> 6;
  const int lane = tid & 63;
  const int l16 = lane & 15;
  const int quad = lane >> 4;

  const _Float16* Qg = QK + h * HEAD_DIM;
  const _Float16* Kg = QK + 1024 + h * HEAD_DIM;
  const _Float16* Vg = Vtg + (size_t)h * HEAD_DIM * T_SEQ;

  const _Float16* qp = Qg + (size_t)(q0 + w * 16 + l16) * 2048;
  halfx8 qa0 = *(const halfx8*)(qp + quad * 8);
  halfx8 qa1 = *(const halfx8*)(qp + 32 + quad * 8);

  const float scale2 = 0.18033688f;  // 0.125 * log2(e)
  const float slope2 = exp2f(-0.5f * (float)(h + 1)) * 1.44269504f;
  const int row_base = q0 + w * 16 + quad * 4;

  const int sr = w * 8 + (lane >> 3);
  const int gg = (lane & 7) ^ ((lane >> 3) & 7);
  const _Float16* Kp = Kg + (size_t)sr * 2048 + gg * 8;
  const _Float16* Vp = Vg + (size_t)sr * 2048 + gg * 8;

  const int m7 = l16 & 7;
  const int cK0 = (quad ^ m7) * 8;
  const int cK1 = cK0 ^ 32;
  const int cV0 = (quad ^ m7) * 8;
  const int cV1 = ((quad + 4) ^ m7) * 8;

#define FA_ISSUE(buf, k0)                                                      \
  {                                                                            \
    async_ld16(Kp + (size_t)(k0) * 2048, &Ks[buf][w * 8][0]);                  \
    async_ld16(Kp + (size_t)((k0) + 32) * 2048, &Ks[buf][32 + w * 8][0]);      \
    async_ld16(Vp + (k0), &Vt[buf][w * 8][0]);                                 \
    async_ld16(Vp + (size_t)32 * 2048 + (k0), &Vt[buf][32 + w * 8][0]);        \
  }

  float m_i[4], l_i[4];
  floatx4 o_acc[4];
#pragma unroll
  for (int r = 0; r < 4; r++) { m_i[r] = -INFINITY; l_i[r] = 0.f; }
#pragma unroll
  for (int c = 0; c < 4; c++) o_acc[c] = (floatx4){0.f, 0.f, 0.f, 0.f};

  FA_ISSUE(0, 0)

  for (int t = 0; t <= qt; t++) {
    const int k0 = t * 64;
    const int buf = t & 1;
    // Loads for tile t were issued one full tile of compute ago -> cheap.
    wait_barrier<0>();
    if (t < qt) FA_ISSUE(buf ^ 1, k0 + 64)

    // ---- S = Q K^T
    float sc[4][4];
#pragma unroll
    for (int sub = 0; sub < 4; sub++) {
      const _Float16* kr = &Ks[buf][sub * 16 + l16][0];
      halfx8 b0 = *(const halfx8*)(kr + cK0);
      halfx8 b1 = *(const halfx8*)(kr + cK1);
      floatx4 acc = (floatx4){0.f, 0.f, 0.f, 0.f};
      acc = __builtin_amdgcn_mfma_f32_16x16x32_f16(qa0, b0, acc, 0, 0, 0);
      acc = __builtin_amdgcn_mfma_f32_16x16x32_f16(qa1, b1, acc, 0, 0, 0);
#pragma unroll
      for (int r = 0; r < 4; r++) sc[sub][r] = acc[r];
    }

    // ---- online softmax: scale/ALiBi/mask, DPP rotate-reduce max
    const bool diag = (t == qt);
    float mx[4];
#pragma unroll
    for (int r = 0; r < 4; r++) {
      const int rg = row_base + r;
      float ab = slope2 * (float)(k0 + l16 - rg);
      mx[r] = m_i[r];
#pragma unroll
      for (int sub = 0; sub < 4; sub++) {
        float s = sc[sub][r] * scale2 + (ab + slope2 * (float)(sub * 16));
        if (diag && (k0 + sub * 16 + l16) > rg) s = -1e30f;
        sc[sub][r] = s;
        mx[r] = fmaxf(mx[r], s);
      }
    }
#pragma unroll
    for (int r = 0; r < 4; r++) DPP_STEP(mx[r], 0x121, OP_MAXF)
#pragma unroll
    for (int r = 0; r < 4; r++) DPP_STEP(mx[r], 0x122, OP_MAXF)
#pragma unroll
    for (int r = 0; r < 4; r++) DPP_STEP(mx[r], 0x124, OP_MAXF)
#pragma unroll
    for (int r = 0; r < 4; r++) DPP_STEP(mx[r], 0x128, OP_MAXF)

    // ---- exp2, Ps store, DPP rotate-reduce sum
    float ls[4], alpha[4];
#pragma unroll
    for (int r = 0; r < 4; r++) {
      alpha[r] = exp2f(m_i[r] - mx[r]);
      m_i[r] = mx[r];
      float l = 0.f;
#pragma unroll
      for (int sub = 0; sub < 4; sub++) {
        float p = exp2f(sc[sub][r] - mx[r]);
        l += p;
        Ps[w][quad * 4 + r][sub * 16 + l16] = (_Float16)p;
      }
      ls[r] = l;
    }
#pragma unroll
    for (int r = 0; r < 4; r++) DPP_STEP(ls[r], 0x121, OP_ADDF)
#pragma unroll
    for (int r = 0; r < 4; r++) DPP_STEP(ls[r], 0x122, OP_ADDF)
#pragma unroll
    for (int r = 0; r < 4; r++) DPP_STEP(ls[r], 0x124, OP_ADDF)
#pragma unroll
    for (int r = 0; r < 4; r++) DPP_STEP(ls[r], 0x128, OP_ADDF)
#pragma unroll
    for (int r = 0; r < 4; r++) {
      l_i[r] = l_i[r] * alpha[r] + ls[r];
#pragma unroll
      for (int c = 0; c < 4; c++) o_acc[c][r] *= alpha[r];
    }

    // ---- O += P V
#pragma unroll
    for (int kh = 0; kh < 2; kh++) {
      halfx8 pa = *(const halfx8*)(&Ps[w][l16][kh * 32 + quad * 8]);
      const int cV = kh ? cV1 : cV0;
#pragma unroll
      for (int c = 0; c < 4; c++) {
        halfx8 vb = *(const halfx8*)(&Vt[buf][c * 16 + l16][cV]);
        o_acc[c] = __builtin_amdgcn_mfma_f32_16x16x32_f16(pa, vb, o_acc[c], 0, 0, 0);
      }
    }
  }

#pragma unroll
  for (int c = 0; c < 4; c++)
#pragma unroll
    for (int r = 0; r < 4; r++)
      out[(size_t)(row_base + r) * D_MODEL + h * HEAD_DIM + c * 16 + l16] =
          (_Float16)(o_acc[c][r] / l_i[r]);
}

extern "C" void kernel_launch(void* const* d_in, const int* in_sizes, int n_in,
                              void* d_out, int out_size, void* d_ws, size_t ws_size,
                              hipStream_t stream) {
  const float* x   = (const float*)d_in[0];
  const float* wq  = (const float*)d_in[3];
  const float* bq  = (const float*)d_in[4];
  const float* wk  = (const float*)d_in[5];
  const float* bk  = (const float*)d_in[6];
  const float* wv  = (const float*)d_in[7];
  const float* bv  = (const float*)d_in[8];
  const float* wo  = (const float*)d_in[9];
  const float* bo  = (const float*)d_in[10];
  const float* w1  = (const float*)d_in[11];
  const float* b1  = (const float*)d_in[12];
  const float* w2  = (const float*)d_in[13];
  const float* b2  = (const float*)d_in[14];
  const float* g1  = (const float*)d_in[15];
  const float* be1 = (const float*)d_in[16];
  const float* g2  = (const float*)d_in[17];
  const float* be2 = (const float*)d_in[18];
  float* out = (float*)d_out;

  const size_t TD = (size_t)T_SEQ * D_MODEL;  // 2M
  char* p = (char*)d_ws;
  float*    x1    = (float*)p;     p += TD * 4;
  float*    bqkv  = (float*)p;     p += 4096 * 4;
  _Float16* xnh   = (_Float16*)p;  p += TD * 2;
  _Float16* QKh   = (_Float16*)p;  p += (size_t)2048 * 2048 * 2;
  _Float16* Vtg   = (_Float16*)p;  p += (size_t)1024 * 2048 * 2;
  _Float16* attnh = (_Float16*)p;  p += TD * 2;
  _Float16* hh    = (_Float16*)p;  p += (size_t)2048 * 4096 * 2;
  _Float16* Wqkvt = (_Float16*)p;  p += (size_t)3 * 1024 * 1024 * 2;
  _Float16* Wot   = (_Float16*)p;  p += (size_t)1024 * 1024 * 2;
  _Float16* W1t   = (_Float16*)p;  p += (size_t)1024 * 4096 * 2;
  _Float16* W2t   = (_Float16*)p;  p += (size_t)4096 * 1024 * 2;

  dim3 blk(256);

  // prep (weights/bias) + LN1 fused
  prep_ln_kernel<<<dim3(12300 + T_SEQ), blk, 0, stream>>>(
      wq, wk, wv, wo, w1, w2, bq, bk, bv, Wqkvt, Wot, W1t, W2t, bqkv,
      x, g1, be1, xnh);

  // fused QKV: Q,K row-major [2048][2048]; V^T [1024][2048]. 384 blocks.
  hgemm_kernel<3, 128, 128><<<dim3(3072 / 128, T_SEQ / 128), blk, 0, stream>>>(
      xnh, Wqkvt, bqkv, nullptr, nullptr, QKh, Vtg, T_SEQ, 3072, 1024);

  flash_attn_kernel<<<dim3(T_SEQ / 64, N_HEADS), blk, 0, stream>>>(QKh, Vtg, attnh);

  // O-proj + residual(x) -> x1 (fp32). 512 blocks.
  hgemm_kernel<2, 64, 64><<<dim3(1024 / 64, T_SEQ / 64), blk, 0, stream>>>(
      attnh, Wot, bo, x, x1, nullptr, nullptr, T_SEQ, 1024, 1024);

  ln_h_kernel<<<T_SEQ, blk, 0, stream>>>(x1, g2, be2, xnh);

  // FFN1 + GELU -> fp16. 512 blocks.
  hgemm_kernel<1, 128, 128><<<dim3(4096 / 128, T_SEQ / 128), blk, 0, stream>>>(
      xnh, W1t, b1, nullptr, nullptr, hh, nullptr, T_SEQ, 4096, 1024);

  // FFN2 + residual(x1) -> out (fp32). 512 blocks, K=4096.
  hgemm_kernel<2, 64, 64><<<dim3(1024 / 64, T_SEQ / 64), blk, 0, stream>>>(
      hh, W2t, b2, x1, out, nullptr, nullptr, T_SEQ, 1024, 4096);
}

// Round 11
// 550.609 us; speedup vs baseline: 1.5981x; 1.0226x over previous
//
#include <hip/hip_runtime.h>
#include <hip/hip_bf16.h>
#include <math.h>

#define T_SEQ 2048
#define D_MODEL 1024
#define N_HEADS 16
#define HEAD_DIM 64
#define FFN_DIM 4096

typedef _Float16 halfx8 __attribute__((ext_vector_type(8)));
typedef _Float16 halfx4 __attribute__((ext_vector_type(4)));
typedef float floatx4 __attribute__((ext_vector_type(4)));

__device__ __forceinline__ void async_ld16(const _Float16* g, _Float16* l) {
  __builtin_amdgcn_global_load_lds(
      (const __attribute__((address_space(1))) unsigned int*)g,
      (__attribute__((address_space(3))) unsigned int*)l, 16, 0, 0);
}

// Fine-grained barrier: wait until <=N vector-mem ops outstanding, s_barrier.
template <int N> __device__ __forceinline__ void wait_barrier();
template <> __device__ __forceinline__ void wait_barrier<0>() {
  asm volatile("s_waitcnt vmcnt(0)\n\ts_barrier" ::: "memory");
}
template <> __device__ __forceinline__ void wait_barrier<2>() {
  asm volatile("s_waitcnt vmcnt(2)\n\ts_barrier" ::: "memory");
}
template <> __device__ __forceinline__ void wait_barrier<3>() {
  asm volatile("s_waitcnt vmcnt(3)\n\ts_barrier" ::: "memory");
}
template <> __device__ __forceinline__ void wait_barrier<4>() {
  asm volatile("s_waitcnt vmcnt(4)\n\ts_barrier" ::: "memory");
}

// DPP 16-lane rotate-reduce step: v = OP(v, row_ror:<CTRL>(v)).
#define DPP_STEP(v, CTRL, OP)                                                 \
  {                                                                           \
    float _t = __int_as_float(__builtin_amdgcn_update_dpp(                    \
        0, __float_as_int(v), CTRL, 0xF, 0xF, true));                         \
    (v) = OP((v), _t);                                                        \
  }
#define OP_MAXF(a, b) fmaxf((a), (b))
#define OP_ADDF(a, b) ((a) + (b))

// ---- fused prep: 6 weight transposes (fp32->fp16 [n][k]) + bias + LN1 ----
__global__ __launch_bounds__(256) void prep_ln_kernel(
    const float* __restrict__ wq, const float* __restrict__ wk,
    const float* __restrict__ wv, const float* __restrict__ wo,
    const float* __restrict__ w1, const float* __restrict__ w2,
    const float* __restrict__ bq, const float* __restrict__ bk,
    const float* __restrict__ bv, _Float16* __restrict__ Wqkvt,
    _Float16* __restrict__ Wot, _Float16* __restrict__ W1t,
    _Float16* __restrict__ W2t, float* __restrict__ bqkv,
    const float* __restrict__ x, const float* __restrict__ g1,
    const float* __restrict__ be1, _Float16* __restrict__ xnh) {
  int bId = blockIdx.x;
  int tid = threadIdx.x;
  if (bId >= 12300) {  // LayerNorm rows
    int row = bId - 12300;
    const float* xr = x + (size_t)row * D_MODEL;
    _Float16* yr = xnh + (size_t)row * D_MODEL;
    int lid = tid & 63, wid = tid >> 6;
    __shared__ float red[8];
    float4 v = *(const float4*)&xr[tid * 4];
    float sum = v.x + v.y + v.z + v.w;
    for (int o = 32; o > 0; o >>= 1) sum += __shfl_down(sum, o, 64);
    if (lid == 0) red[wid] = sum;
    __syncthreads();
    if (tid == 0) { float t = 0; for (int i = 0; i < 4; i++) t += red[i]; red[0] = t; }
    __syncthreads();
    float mu = red[0] * (1.0f / D_MODEL);
    __syncthreads();
    float dx = v.x - mu, dy = v.y - mu, dz = v.z - mu, dw = v.w - mu;
    float vs = dx * dx + dy * dy + dz * dz + dw * dw;
    for (int o = 32; o > 0; o >>= 1) vs += __shfl_down(vs, o, 64);
    if (lid == 0) red[wid] = vs;
    __syncthreads();
    if (tid == 0) { float t = 0; for (int i = 0; i < 4; i++) t += red[i]; red[0] = t; }
    __syncthreads();
    float rstd = rsqrtf(red[0] * (1.0f / D_MODEL) + 1e-5f);
    float4 gv = *(const float4*)&g1[tid * 4];
    float4 bv4 = *(const float4*)&be1[tid * 4];
    halfx4 o;
    o[0] = (_Float16)(dx * rstd * gv.x + bv4.x);
    o[1] = (_Float16)(dy * rstd * gv.y + bv4.y);
    o[2] = (_Float16)(dz * rstd * gv.z + bv4.z);
    o[3] = (_Float16)(dw * rstd * gv.w + bv4.w);
    *(halfx4*)&yr[tid * 4] = o;
    return;
  }
  if (bId >= 12288) {  // bias pack
    int i = (bId - 12288) * 256 + tid;
    if (i < 1024) bqkv[i] = bq[i];
    else if (i < 2048) bqkv[i] = bk[i - 1024];
    else bqkv[i] = bv[i - 2048];
    return;
  }
  const float* in; _Float16* outp; int K, N, t;
  if (bId < 1024)      { in = wq; outp = Wqkvt;                 K = 1024; N = 1024; t = bId; }
  else if (bId < 2048) { in = wk; outp = Wqkvt + 1024 * 1024;   K = 1024; N = 1024; t = bId - 1024; }
  else if (bId < 3072) { in = wv; outp = Wqkvt + 2 * 1024 * 1024; K = 1024; N = 1024; t = bId - 2048; }
  else if (bId < 4096) { in = wo; outp = Wot;                   K = 1024; N = 1024; t = bId - 3072; }
  else if (bId < 8192) { in = w1; outp = W1t;                   K = 1024; N = 4096; t = bId - 4096; }
  else                 { in = w2; outp = W2t;                   K = 4096; N = 1024; t = bId - 8192; }
  int ntn = N / 32;
  int tk = (t / ntn) * 32, tn = (t % ntn) * 32;

  __shared__ float tile[32][33];
  int r = tid >> 3, c = (tid & 7) * 4;
  float4 v = *(const float4*)&in[(size_t)(tk + r) * N + tn + c];
  tile[r][c] = v.x; tile[r][c + 1] = v.y; tile[r][c + 2] = v.z; tile[r][c + 3] = v.w;
  __syncthreads();
  halfx4 o;
  o[0] = (_Float16)tile[c][r];
  o[1] = (_Float16)tile[c + 1][r];
  o[2] = (_Float16)tile[c + 2][r];
  o[3] = (_Float16)tile[c + 3][r];
  *(halfx4*)&outp[(size_t)(tn + r) * K + tk + c] = o;
}

// ---------------- LayerNorm (standalone, for LN2) ----------------
__global__ __launch_bounds__(256) void ln_h_kernel(
    const float* __restrict__ x, const float* __restrict__ g,
    const float* __restrict__ b, _Float16* __restrict__ y) {
  int row = blockIdx.x;
  const float* xr = x + (size_t)row * D_MODEL;
  _Float16* yr = y + (size_t)row * D_MODEL;
  int tid = threadIdx.x;
  int lid = tid & 63, wid = tid >> 6;
  __shared__ float red[8];

  float4 v = *(const float4*)&xr[tid * 4];
  float sum = v.x + v.y + v.z + v.w;
  for (int o = 32; o > 0; o >>= 1) sum += __shfl_down(sum, o, 64);
  if (lid == 0) red[wid] = sum;
  __syncthreads();
  if (tid == 0) { float t = 0; for (int i = 0; i < 4; i++) t += red[i]; red[0] = t; }
  __syncthreads();
  float mu = red[0] * (1.0f / D_MODEL);
  __syncthreads();

  float dx = v.x - mu, dy = v.y - mu, dz = v.z - mu, dw = v.w - mu;
  float vs = dx * dx + dy * dy + dz * dz + dw * dw;
  for (int o = 32; o > 0; o >>= 1) vs += __shfl_down(vs, o, 64);
  if (lid == 0) red[wid] = vs;
  __syncthreads();
  if (tid == 0) { float t = 0; for (int i = 0; i < 4; i++) t += red[i]; red[0] = t; }
  __syncthreads();
  float rstd = rsqrtf(red[0] * (1.0f / D_MODEL) + 1e-5f);

  float4 gv = *(const float4*)&g[tid * 4];
  float4 bv = *(const float4*)&b[tid * 4];
  halfx4 o;
  o[0] = (_Float16)(dx * rstd * gv.x + bv.x);
  o[1] = (_Float16)(dy * rstd * gv.y + bv.y);
  o[2] = (_Float16)(dz * rstd * gv.z + bv.z);
  o[3] = (_Float16)(dw * rstd * gv.w + bv.w);
  *(halfx4*)&yr[tid * 4] = o;
}

// ---------------- MFMA f16 GEMM (ring-3, 2-deep prefetch) ----------------
template <int MODE, int BM, int BN>
__global__ __launch_bounds__(256) void hgemm_kernel(
    const _Float16* __restrict__ A, const _Float16* __restrict__ Bt,
    const float* __restrict__ bias, const float* __restrict__ res,
    float* __restrict__ Cf, _Float16* __restrict__ Ch,
    _Float16* __restrict__ Vtg, int M, int N, int K) {
  constexpr int TM = BM / 32;
  constexpr int TN = BN / 32;
  constexpr int AR = BM / 64;
  constexpr int BR = BN / 64;
  constexpr int L = AR + BR;
  __shared__ _Float16 As[3][BM][32];
  __shared__ _Float16 Bs[3][BN][32];
  const int tid = threadIdx.x;
  const int w = tid >> 6, lane = tid & 63;
  const int l16 = lane & 15, quad = lane >> 4;
  const int m0 = blockIdx.y * BM, n0 = blockIdx.x * BN;
  const int wm = (w >> 1) * (BM / 2), wn = (w & 1) * (BN / 2);

  floatx4 acc[TM][TN];
#pragma unroll
  for (int i = 0; i < TM; i++)
#pragma unroll
    for (int j = 0; j < TN; j++) acc[i][j] = (floatx4){0.f, 0.f, 0.f, 0.f};

  const int srow = w * 16 + (lane >> 2);
  const int gg = (lane & 3) ^ ((srow >> 1) & 3);
  const _Float16* Agp = A + (size_t)(m0 + srow) * K + gg * 8;
  const _Float16* Bgp = Bt + (size_t)(n0 + srow) * K + gg * 8;

  const int colA = (quad ^ ((l16 >> 1) & 3)) * 8;

  const int NIT = K / 32;
#define HG_ISSUE(buf, k0)                                                     \
  {                                                                           \
    _Pragma("unroll") for (int i = 0; i < AR; i++)                            \
        async_ld16(Agp + (k0) + (size_t)i * 64 * K, &As[buf][i * 64 + w * 16][0]); \
    _Pragma("unroll") for (int i = 0; i < BR; i++)                            \
        async_ld16(Bgp + (k0) + (size_t)i * 64 * K, &Bs[buf][i * 64 + w * 16][0]); \
  }
  HG_ISSUE(0, 0)
  HG_ISSUE(1, 32)

  for (int it = 0; it < NIT; it++) {
    const int buf = it % 3;
    if (it + 1 < NIT) wait_barrier<L>();
    else wait_barrier<0>();  // tail
    if (it + 2 < NIT) HG_ISSUE((it + 2) % 3, (it + 2) * 32)
    halfx8 af[TM], bf[TN];
#pragma unroll
    for (int mt = 0; mt < TM; mt++)
      af[mt] = *(const halfx8*)&As[buf][wm + mt * 16 + l16][colA];
#pragma unroll
    for (int nt = 0; nt < TN; nt++)
      bf[nt] = *(const halfx8*)&Bs[buf][wn + nt * 16 + l16][colA];
#pragma unroll
    for (int mt = 0; mt < TM; mt++)
#pragma unroll
      for (int nt = 0; nt < TN; nt++)
        acc[mt][nt] = __builtin_amdgcn_mfma_f32_16x16x32_f16(af[mt], bf[nt], acc[mt][nt], 0, 0, 0);
  }

#pragma unroll
  for (int mt = 0; mt < TM; mt++) {
    int row0 = m0 + wm + mt * 16 + quad * 4;
#pragma unroll
    for (int nt = 0; nt < TN; nt++) {
      int col = n0 + wn + nt * 16 + l16;
      float bv = bias[col];
      float vv[4];
#pragma unroll
      for (int r = 0; r < 4; r++) {
        float v = acc[mt][nt][r] + bv;
        if (MODE == 1) v = 0.5f * v * (1.0f + erff(v * 0.70710678118f));
        vv[r] = v;
      }
      if (MODE == 2) {
#pragma unroll
        for (int r = 0; r < 4; r++)
          Cf[(size_t)(row0 + r) * N + col] = vv[r] + res[(size_t)(row0 + r) * N + col];
      } else if (MODE == 3) {
        if (col < 2048) {
#pragma unroll
          for (int r = 0; r < 4; r++)
            Ch[(size_t)(row0 + r) * 2048 + col] = (_Float16)vv[r];
        } else {
          halfx4 pk;
#pragma unroll
          for (int r = 0; r < 4; r++) pk[r] = (_Float16)vv[r];
          *(halfx4*)&Vtg[(size_t)(col - 2048) * T_SEQ + row0] = pk;
        }
      } else {
#pragma unroll
        for (int r = 0; r < 4; r++)
          Ch[(size_t)(row0 + r) * N + col] = (_Float16)vv[r];
      }
    }
  }
}

// ---------------- Flash attention: split-K (flash-decode style) ----------
// blockIdx.x in [0,48): bx<32 -> split blocks for qt=16..31 (part 0/1 each
// cover half the K-tile range, write fp32 partials); bx>=32 -> single blocks
// qt=15..0 (final write). Max 16 K-iterations per block (makespan balance).
#define LROW 72
__global__ __launch_bounds__(256) void flash_attn_kernel(
    const _Float16* __restrict__ QK, const _Float16* __restrict__ Vtg,
    _Float16* __restrict__ out, float* __restrict__ Opart,
    float* __restrict__ Mpart, float* __restrict__ Lpart) {
  __shared__ _Float16 Ks[2][64][64];
  __shared__ _Float16 Vt[2][64][64];
  __shared__ _Float16 Ps[4][16][LROW];

  const int h = blockIdx.y;
  const int bx = blockIdx.x;
  int qt, tlo, thi, split;
  if (bx < 32) {
    qt = 31 - (bx >> 1);
    split = bx & 1;
    int nt = qt + 1, nt1 = nt >> 1;
    tlo = split ? nt1 : 0;
    thi = split ? nt : nt1;
  } else {
    qt = 47 - bx;  // 15..0, heavy first
    split = -1;
    tlo = 0;
    thi = qt + 1;
  }
  const int q0 = qt * 64;
  const int tid = threadIdx.x;
  const int w = tid >> 6;
  const int lane = tid & 63;
  const int l16 = lane & 15;
  const int quad = lane >> 4;

  const _Float16* Qg = QK + h * HEAD_DIM;
  const _Float16* Kg = QK + 1024 + h * HEAD_DIM;
  const _Float16* Vg = Vtg + (size_t)h * HEAD_DIM * T_SEQ;

  const _Float16* qp = Qg + (size_t)(q0 + w * 16 + l16) * 2048;
  halfx8 qa0 = *(const halfx8*)(qp + quad * 8);
  halfx8 qa1 = *(const halfx8*)(qp + 32 + quad * 8);

  const float scale2 = 0.18033688f;  // 0.125 * log2(e)
  const float slope2 = exp2f(-0.5f * (float)(h + 1)) * 1.44269504f;
  const int row_base = q0 + w * 16 + quad * 4;

  const int sr = w * 8 + (lane >> 3);
  const int gg = (lane & 7) ^ ((lane >> 3) & 7);
  const _Float16* Kp = Kg + (size_t)sr * 2048 + gg * 8;
  const _Float16* Vp = Vg + (size_t)sr * 2048 + gg * 8;

  const int m7 = l16 & 7;
  const int cK0 = (quad ^ m7) * 8;
  const int cK1 = cK0 ^ 32;
  const int cV0 = (quad ^ m7) * 8;
  const int cV1 = ((quad + 4) ^ m7) * 8;

#define FA_ISSUE(buf, k0)                                                      \
  {                                                                            \
    async_ld16(Kp + (size_t)(k0) * 2048, &Ks[buf][w * 8][0]);                  \
    async_ld16(Kp + (size_t)((k0) + 32) * 2048, &Ks[buf][32 + w * 8][0]);      \
    async_ld16(Vp + (k0), &Vt[buf][w * 8][0]);                                 \
    async_ld16(Vp + (size_t)32 * 2048 + (k0), &Vt[buf][32 + w * 8][0]);        \
  }

  float m_i[4], l_i[4];
  floatx4 o_acc[4];
#pragma unroll
  for (int r = 0; r < 4; r++) { m_i[r] = -INFINITY; l_i[r] = 0.f; }
#pragma unroll
  for (int c = 0; c < 4; c++) o_acc[c] = (floatx4){0.f, 0.f, 0.f, 0.f};

  FA_ISSUE(0, tlo * 64)

  for (int t = tlo; t < thi; t++) {
    const int k0 = t * 64;
    const int buf = (t - tlo) & 1;
    wait_barrier<0>();
    if (t + 1 < thi) FA_ISSUE(buf ^ 1, (t + 1) * 64)

    // ---- S = Q K^T
    float sc[4][4];
#pragma unroll
    for (int sub = 0; sub < 4; sub++) {
      const _Float16* kr = &Ks[buf][sub * 16 + l16][0];
      halfx8 b0 = *(const halfx8*)(kr + cK0);
      halfx8 b1 = *(const halfx8*)(kr + cK1);
      floatx4 acc = (floatx4){0.f, 0.f, 0.f, 0.f};
      acc = __builtin_amdgcn_mfma_f32_16x16x32_f16(qa0, b0, acc, 0, 0, 0);
      acc = __builtin_amdgcn_mfma_f32_16x16x32_f16(qa1, b1, acc, 0, 0, 0);
#pragma unroll
      for (int r = 0; r < 4; r++) sc[sub][r] = acc[r];
    }

    // ---- online softmax: scale/ALiBi/mask, DPP rotate-reduce max
    const bool diag = (t == qt);
    float mx[4];
#pragma unroll
    for (int r = 0; r < 4; r++) {
      const int rg = row_base + r;
      float ab = slope2 * (float)(k0 + l16 - rg);
      mx[r] = m_i[r];
#pragma unroll
      for (int sub = 0; sub < 4; sub++) {
        float s = sc[sub][r] * scale2 + (ab + slope2 * (float)(sub * 16));
        if (diag && (k0 + sub * 16 + l16) > rg) s = -1e30f;
        sc[sub][r] = s;
        mx[r] = fmaxf(mx[r], s);
      }
    }
#pragma unroll
    for (int r = 0; r < 4; r++) DPP_STEP(mx[r], 0x121, OP_MAXF)
#pragma unroll
    for (int r = 0; r < 4; r++) DPP_STEP(mx[r], 0x122, OP_MAXF)
#pragma unroll
    for (int r = 0; r < 4; r++) DPP_STEP(mx[r], 0x124, OP_MAXF)
#pragma unroll
    for (int r = 0; r < 4; r++) DPP_STEP(mx[r], 0x128, OP_MAXF)

    // ---- exp2, Ps store, DPP rotate-reduce sum
    float ls[4], alpha[4];
#pragma unroll
    for (int r = 0; r < 4; r++) {
      alpha[r] = exp2f(m_i[r] - mx[r]);
      m_i[r] = mx[r];
      float l = 0.f;
#pragma unroll
      for (int sub = 0; sub < 4; sub++) {
        float p = exp2f(sc[sub][r] - mx[r]);
        l += p;
        Ps[w][quad * 4 + r][sub * 16 + l16] = (_Float16)p;
      }
      ls[r] = l;
    }
#pragma unroll
    for (int r = 0; r < 4; r++) DPP_STEP(ls[r], 0x121, OP_ADDF)
#pragma unroll
    for (int r = 0; r < 4; r++) DPP_STEP(ls[r], 0x122, OP_ADDF)
#pragma unroll
    for (int r = 0; r < 4; r++) DPP_STEP(ls[r], 0x124, OP_ADDF)
#pragma unroll
    for (int r = 0; r < 4; r++) DPP_STEP(ls[r], 0x128, OP_ADDF)
#pragma unroll
    for (int r = 0; r < 4; r++) {
      l_i[r] = l_i[r] * alpha[r] + ls[r];
#pragma unroll
      for (int c = 0; c < 4; c++) o_acc[c][r] *= alpha[r];
    }

    // ---- O += P V
#pragma unroll
    for (int kh = 0; kh < 2; kh++) {
      halfx8 pa = *(const halfx8*)(&Ps[w][l16][kh * 32 + quad * 8]);
      const int cV = kh ? cV1 : cV0;
#pragma unroll
      for (int c = 0; c < 4; c++) {
        halfx8 vb = *(const halfx8*)(&Vt[buf][c * 16 + l16][cV]);
        o_acc[c] = __builtin_amdgcn_mfma_f32_16x16x32_f16(pa, vb, o_acc[c], 0, 0, 0);
      }
    }
  }

  if (split < 0) {
#pragma unroll
    for (int c = 0; c < 4; c++)
#pragma unroll
      for (int r = 0; r < 4; r++)
        out[(size_t)(row_base + r) * D_MODEL + h * HEAD_DIM + c * 16 + l16] =
            (_Float16)(o_acc[c][r] / l_i[r]);
  } else {
    // unnormalized fp32 partials; rows are q0.. with q0 >= 1024
    float* Ob = Opart + (((size_t)split * 16 + h) * 1024) * 64;
#pragma unroll
    for (int r = 0; r < 4; r++) {
      int qrel = row_base + r - 1024;
#pragma unroll
      for (int c = 0; c < 4; c++)
        Ob[(size_t)qrel * 64 + c * 16 + l16] = o_acc[c][r];
      if (l16 == 0) {
        int pq = split * 16384 + h * 1024 + qrel;
        Mpart[pq] = m_i[r];
        Lpart[pq] = l_i[r];
      }
    }
  }
}

// ---------------- Split-K combine: merge two partials per row ----------------
__global__ __launch_bounds__(256) void fa_combine_kernel(
    const float* __restrict__ Opart, const float* __restrict__ Mpart,
    const float* __restrict__ Lpart, _Float16* __restrict__ out) {
  int g = blockIdx.x * 256 + threadIdx.x;  // 16h * 1024q * 16 d-groups
  int d4 = (g & 15) * 4;
  int q = (g >> 4) & 1023;
  int h = g >> 14;
  int pq = h * 1024 + q;
  float m0 = Mpart[pq], m1 = Mpart[16384 + pq];
  float l0 = Lpart[pq], l1 = Lpart[16384 + pq];
  float M = fmaxf(m0, m1);
  float a0 = exp2f(m0 - M), a1 = exp2f(m1 - M);
  float inv = 1.0f / (a0 * l0 + a1 * l1);
  const float* O0 = Opart + ((size_t)h * 1024 + q) * 64 + d4;
  const float* O1 = O0 + (size_t)16 * 1024 * 64;
  halfx4 o;
#pragma unroll
  for (int j = 0; j < 4; j++)
    o[j] = (_Float16)((a0 * O0[j] + a1 * O1[j]) * inv);
  *(halfx4*)&out[(size_t)(q + 1024) * D_MODEL + h * HEAD_DIM + d4] = o;
}

extern "C" void kernel_launch(void* const* d_in, const int* in_sizes, int n_in,
                              void* d_out, int out_size, void* d_ws, size_t ws_size,
                              hipStream_t stream) {
  const float* x   = (const float*)d_in[0];
  const float* wq  = (const float*)d_in[3];
  const float* bq  = (const float*)d_in[4];
  const float* wk  = (const float*)d_in[5];
  const float* bk  = (const float*)d_in[6];
  const float* wv  = (const float*)d_in[7];
  const float* bv  = (const float*)d_in[8];
  const float* wo  = (const float*)d_in[9];
  const float* bo  = (const float*)d_in[10];
  const float* w1  = (const float*)d_in[11];
  const float* b1  = (const float*)d_in[12];
  const float* w2  = (const float*)d_in[13];
  const float* b2  = (const float*)d_in[14];
  const float* g1  = (const float*)d_in[15];
  const float* be1 = (const float*)d_in[16];
  const float* g2  = (const float*)d_in[17];
  const float* be2 = (const float*)d_in[18];
  float* out = (float*)d_out;

  const size_t TD = (size_t)T_SEQ * D_MODEL;  // 2M
  char* p = (char*)d_ws;
  float*    x1    = (float*)p;     p += TD * 4;
  float*    bqkv  = (float*)p;     p += 4096 * 4;
  _Float16* xnh   = (_Float16*)p;  p += TD * 2;
  _Float16* QKh   = (_Float16*)p;  p += (size_t)2048 * 2048 * 2;
  _Float16* Vtg   = (_Float16*)p;  p += (size_t)1024 * 2048 * 2;
  _Float16* attnh = (_Float16*)p;  p += TD * 2;
  _Float16* hh    = (_Float16*)p;  p += (size_t)2048 * 4096 * 2;
  _Float16* Wqkvt = (_Float16*)p;  p += (size_t)3 * 1024 * 1024 * 2;
  _Float16* Wot   = (_Float16*)p;  p += (size_t)1024 * 1024 * 2;
  _Float16* W1t   = (_Float16*)p;  p += (size_t)1024 * 4096 * 2;
  _Float16* W2t   = (_Float16*)p;  p += (size_t)4096 * 1024 * 2;
  float*    Opart = (float*)p;     p += (size_t)2 * 16 * 1024 * 64 * 4;  // 8 MB
  float*    Mpart = (float*)p;     p += (size_t)2 * 16 * 1024 * 4;
  float*    Lpart = (float*)p;     p += (size_t)2 * 16 * 1024 * 4;

  dim3 blk(256);

  // prep (weights/bias) + LN1 fused
  prep_ln_kernel<<<dim3(12300 + T_SEQ), blk, 0, stream>>>(
      wq, wk, wv, wo, w1, w2, bq, bk, bv, Wqkvt, Wot, W1t, W2t, bqkv,
      x, g1, be1, xnh);

  // fused QKV: Q,K row-major [2048][2048]; V^T [1024][2048]. 384 blocks.
  hgemm_kernel<3, 128, 128><<<dim3(3072 / 128, T_SEQ / 128), blk, 0, stream>>>(
      xnh, Wqkvt, bqkv, nullptr, nullptr, QKh, Vtg, T_SEQ, 3072, 1024);

  // split-K flash: 48 x 16 blocks (<=16 K-iters each)
  flash_attn_kernel<<<dim3(48, N_HEADS), blk, 0, stream>>>(
      QKh, Vtg, attnh, Opart, Mpart, Lpart);
  fa_combine_kernel<<<dim3(1024), blk, 0, stream>>>(Opart, Mpart, Lpart, attnh);

  // O-proj + residual(x) -> x1 (fp32). 512 blocks.
  hgemm_kernel<2, 64, 64><<<dim3(1024 / 64, T_SEQ / 64), blk, 0, stream>>>(
      attnh, Wot, bo, x, x1, nullptr, nullptr, T_SEQ, 1024, 1024);

  ln_h_kernel<<<T_SEQ, blk, 0, stream>>>(x1, g2, be2, xnh);

  // FFN1 + GELU -> fp16. 512 blocks.
  hgemm_kernel<1, 128, 128><<<dim3(4096 / 128, T_SEQ / 128), blk, 0, stream>>>(
      xnh, W1t, b1, nullptr, nullptr, hh, nullptr, T_SEQ, 4096, 1024);

  // FFN2 + residual(x1) -> out (fp32). 512 blocks, K=4096.
  hgemm_kernel<2, 64, 64><<<dim3(1024 / 64, T_SEQ / 64), blk, 0, stream>>>(
      hh, W2t, b2, x1, out, nullptr, nullptr, T_SEQ, 1024, 4096);
}